// Round 1
// baseline (1071.415 us; speedup 1.0000x reference)
//
#include <hip/hip_runtime.h>
#include <hip/hip_bf16.h>
#include <type_traits>

typedef __bf16 bf16_t;
typedef __attribute__((ext_vector_type(8))) __bf16 bf16x8;
typedef __attribute__((ext_vector_type(4))) float f32x4;

#define B_ 2
#define S_ 2048
#define D_ 1024
#define H_ 16
#define DK_ 64

// split a run of 8 fp32 into bf16 hi + bf16 lo (residual) parts
__device__ inline void split8(const float* __restrict__ p, bf16x8& h, bf16x8& l) {
    float4 x0 = *(const float4*)p;
    float4 x1 = *(const float4*)(p + 4);
    float xs[8] = {x0.x, x0.y, x0.z, x0.w, x1.x, x1.y, x1.z, x1.w};
#pragma unroll
    for (int i = 0; i < 8; ++i) {
        bf16_t hh = (bf16_t)xs[i];
        h[i] = hh;
        l[i] = (bf16_t)(xs[i] - (float)hh);
    }
}
__device__ inline void hi8(const float* __restrict__ p, bf16x8& h) {
    float4 x0 = *(const float4*)p;
    float4 x1 = *(const float4*)(p + 4);
    float xs[8] = {x0.x, x0.y, x0.z, x0.w, x1.x, x1.y, x1.z, x1.w};
#pragma unroll
    for (int i = 0; i < 8; ++i) h[i] = (bf16_t)xs[i];
}

// ---------------------------------------------------------------------------
// GEMM: Y[M,N] = A[M,K] @ W[N,K]^T + bias[N].  (unchanged this round)
// ---------------------------------------------------------------------------
template <typename AT, typename OT, bool SPLIT>
__global__ __launch_bounds__(256) void gemm_bt(
    const AT* __restrict__ A,
    const float* __restrict__ W,
    const float* __restrict__ bias,
    OT* __restrict__ Y,
    int M, int N, int K)
{
    const int NB = N >> 6;
    const int bm = blockIdx.x / NB;
    const int bn = blockIdx.x % NB;
    const int tid  = threadIdx.x;
    const int wave = tid >> 6;
    const int lane = tid & 63;
    const int l16  = lane & 15;
    const int quad = lane >> 4;
    const int wm = wave >> 1, wn = wave & 1;

    __shared__ bf16_t Ah[64][40];
    __shared__ bf16_t Wh[64][40];
    __shared__ bf16_t Al[SPLIT ? 64 : 1][40];
    __shared__ bf16_t Wl[SPLIT ? 64 : 1][40];

    const int srow = tid >> 2;        // 0..63
    const int scol = (tid & 3) * 8;   // 0,8,16,24

    f32x4 acc[2][2];
#pragma unroll
    for (int i = 0; i < 2; ++i)
#pragma unroll
        for (int j = 0; j < 2; ++j) acc[i][j] = (f32x4){0.f, 0.f, 0.f, 0.f};

    const AT*    Arow = A + (size_t)(bm * 64 + srow) * K + scol;
    const float* Wrow = W + (size_t)(bn * 64 + srow) * K + scol;

    for (int k0 = 0; k0 < K; k0 += 32) {
        if constexpr (std::is_same_v<AT, float>) {
            bf16x8 ah, al;
            if constexpr (SPLIT) {
                split8(Arow + k0, ah, al);
                *(bf16x8*)(&Al[srow][scol]) = al;
            } else {
                hi8(Arow + k0, ah);
            }
            *(bf16x8*)(&Ah[srow][scol]) = ah;
        } else {
            *(bf16x8*)(&Ah[srow][scol]) = *(const bf16x8*)(Arow + k0);
        }
        {
            bf16x8 wh, wl;
            if constexpr (SPLIT) {
                split8(Wrow + k0, wh, wl);
                *(bf16x8*)(&Wl[srow][scol]) = wl;
            } else {
                hi8(Wrow + k0, wh);
            }
            *(bf16x8*)(&Wh[srow][scol]) = wh;
        }
        __syncthreads();

        bf16x8 afh[2], bfh[2], afl[2], bfl[2];
#pragma unroll
        for (int mi = 0; mi < 2; ++mi) {
            afh[mi] = *(const bf16x8*)(&Ah[wm * 32 + mi * 16 + l16][quad * 8]);
            if constexpr (SPLIT)
                afl[mi] = *(const bf16x8*)(&Al[wm * 32 + mi * 16 + l16][quad * 8]);
        }
#pragma unroll
        for (int ni = 0; ni < 2; ++ni) {
            bfh[ni] = *(const bf16x8*)(&Wh[wn * 32 + ni * 16 + l16][quad * 8]);
            if constexpr (SPLIT)
                bfl[ni] = *(const bf16x8*)(&Wl[wn * 32 + ni * 16 + l16][quad * 8]);
        }

#pragma unroll
        for (int mi = 0; mi < 2; ++mi)
#pragma unroll
            for (int ni = 0; ni < 2; ++ni) {
                acc[mi][ni] = __builtin_amdgcn_mfma_f32_16x16x32_bf16(
                    afh[mi], bfh[ni], acc[mi][ni], 0, 0, 0);
                if constexpr (SPLIT) {
                    acc[mi][ni] = __builtin_amdgcn_mfma_f32_16x16x32_bf16(
                        afl[mi], bfh[ni], acc[mi][ni], 0, 0, 0);
                    acc[mi][ni] = __builtin_amdgcn_mfma_f32_16x16x32_bf16(
                        afh[mi], bfl[ni], acc[mi][ni], 0, 0, 0);
                }
            }
        __syncthreads();
    }

#pragma unroll
    for (int ni = 0; ni < 2; ++ni) {
        const int col = bn * 64 + wn * 32 + ni * 16 + l16;
        const float bv = bias[col];
#pragma unroll
        for (int mi = 0; mi < 2; ++mi) {
#pragma unroll
            for (int r = 0; r < 4; ++r) {
                const int row = bm * 64 + wm * 32 + mi * 16 + quad * 4 + r;
                Y[(size_t)row * N + col] = (OT)(acc[mi][ni][r] + bv);
            }
        }
    }
}

// ---------------------------------------------------------------------------
// Pack the int32 mask [B,S,S] into bits (1 = masked). One u64 per 64 j's.
// ---------------------------------------------------------------------------
__global__ __launch_bounds__(256) void pack_mask(
    const int* __restrict__ mask,
    unsigned long long* __restrict__ pk)
{
    const size_t nwords = (size_t)B_ * S_ * S_ / 64;  // 131072
    const int lane = threadIdx.x & 63;
    size_t w = (size_t)blockIdx.x * 4 + (threadIdx.x >> 6);
    const size_t stride = (size_t)gridDim.x * 4;
    for (; w < nwords; w += stride) {
        const int m = mask[w * 64 + lane];
        const unsigned long long bb = __ballot(m != 0);
        if (lane == 0) pk[w] = bb;
    }
}

// ---------------------------------------------------------------------------
// Single-pass attention with deferred normalization.
// Per block = (b, h, 64 q-rows); wave w owns 16 q-rows.
// K hi/lo is split ONCE per block per 32-j tile, cooperatively, into LDS
// (previously each of 4 waves split the same tile, twice across 2 passes).
// Writes UNNORMALIZED e = exp(s/8) to wout (rescaled by a later kernel,
// bit-identical to computing e*norm here); accumulates lsum and the PV
// product with unnormalized bf16 weights, scales ctx by norm at the end.
// ---------------------------------------------------------------------------
__global__ __launch_bounds__(256) void attn_kernel(
    const float*  __restrict__ qp,     // [B,S,D] fp32
    const float*  __restrict__ kp,     // [B,S,D] fp32
    const bf16_t* __restrict__ vp,     // [B,S,D] bf16
    const unsigned* __restrict__ pm,   // packed mask bits [B,S,S/32]
    float* __restrict__ wout,          // [B,H,S,S] fp32 (unnormalized e)
    float* __restrict__ normbuf,       // [B,H,S] fp32 (2048/lsum)
    bf16_t* __restrict__ ctx)          // [B,S,D] bf16
{
    const int bid = blockIdx.x;       // B*H*(S/64) = 1024
    const int qt = bid & 31;
    const int h  = (bid >> 5) & 15;
    const int b  = bid >> 9;
    const int tid  = threadIdx.x;
    const int wave = tid >> 6;
    const int lane = tid & 63;
    const int l16  = lane & 15;
    const int quad = lane >> 4;

    const int q0 = qt * 64 + wave * 16;

    __shared__ bf16_t Kh[32][72];        // [j][dk], +8 pad -> 2-way banks max
    __shared__ bf16_t Kl[32][72];
    __shared__ bf16_t vT[64][40];        // [dk][j]
    __shared__ bf16_t wl[4][16][40];     // per-wave w tile [q][j]

    // q fragments (A operand), hi/lo, held in registers
    const float* qbase = qp + ((size_t)(b * S_ + q0 + l16)) * D_ + h * DK_ + quad * 8;
    bf16x8 qh0, ql0, qh1, ql1;
    split8(qbase, qh0, ql0);
    split8(qbase + 32, qh1, ql1);

    const float scale = 0.125f;  // 1/sqrt(64)

    // cooperative staging indices (256 threads cover 32 rows x 64 cols)
    const int srow = tid >> 3;        // 0..31 (j within tile)
    const int scol = (tid & 7) * 8;   // 0..56 (dk)
    const float*  kst = kp + (size_t)b * S_ * D_ + h * DK_;
    const bf16_t* vst = vp + (size_t)b * S_ * D_ + h * DK_;

    const unsigned* pmrow = pm + (size_t)b * S_ * (S_ / 32);
    const size_t wbase = ((size_t)(b * H_ + h)) * S_ * S_;

    float lsum[4] = {0.f, 0.f, 0.f, 0.f};
    f32x4 acc[4];
#pragma unroll
    for (int t = 0; t < 4; ++t) acc[t] = (f32x4){0.f, 0.f, 0.f, 0.f};

    for (int j0 = 0; j0 < S_; j0 += 32) {
        // ---- cooperative stage: K hi/lo split + V^T, once per block ----
        {
            bf16x8 kh, kl;
            split8(kst + (size_t)(j0 + srow) * D_ + scol, kh, kl);
            *(bf16x8*)(&Kh[srow][scol]) = kh;
            *(bf16x8*)(&Kl[srow][scol]) = kl;

            const bf16x8 vv = *(const bf16x8*)(vst + (size_t)(j0 + srow) * D_ + scol);
#pragma unroll
            for (int i = 0; i < 8; ++i) vT[scol + i][srow] = vv[i];
        }
        // mask words: one u32 covers j0..j0+31 for row q (uniform across l16)
        unsigned mw[4];
#pragma unroll
        for (int r = 0; r < 4; ++r) {
            const int q = q0 + quad * 4 + r;
            mw[r] = pmrow[(size_t)q * (S_ / 32) + (j0 >> 5)];
        }
        __syncthreads();

#pragma unroll
        for (int sub = 0; sub < 2; ++sub) {
            const int rr = sub * 16 + l16;
            const bf16x8 kh0 = *(const bf16x8*)(&Kh[rr][quad * 8]);
            const bf16x8 kh1 = *(const bf16x8*)(&Kh[rr][32 + quad * 8]);
            const bf16x8 kl0 = *(const bf16x8*)(&Kl[rr][quad * 8]);
            const bf16x8 kl1 = *(const bf16x8*)(&Kl[rr][32 + quad * 8]);
            f32x4 c = (f32x4){0.f, 0.f, 0.f, 0.f};
            c = __builtin_amdgcn_mfma_f32_16x16x32_bf16(qh0, kh0, c, 0, 0, 0);
            c = __builtin_amdgcn_mfma_f32_16x16x32_bf16(qh1, kh1, c, 0, 0, 0);
            c = __builtin_amdgcn_mfma_f32_16x16x32_bf16(ql0, kh0, c, 0, 0, 0);
            c = __builtin_amdgcn_mfma_f32_16x16x32_bf16(ql1, kh1, c, 0, 0, 0);
            c = __builtin_amdgcn_mfma_f32_16x16x32_bf16(qh0, kl0, c, 0, 0, 0);
            c = __builtin_amdgcn_mfma_f32_16x16x32_bf16(qh1, kl1, c, 0, 0, 0);
            const int jt = j0 + sub * 16;
#pragma unroll
            for (int r = 0; r < 4; ++r) {
                const int q = q0 + quad * 4 + r;
                const int msk = (mw[r] >> (sub * 16 + l16)) & 1;
                const float e = msk ? 0.f : __expf(c[r] * scale);
                lsum[r] += e;
                // unnormalized; nontemporal to protect L2-resident K/V/mask
                __builtin_nontemporal_store(e, &wout[wbase + (size_t)q * S_ + jt + l16]);
                wl[wave][quad * 4 + r][sub * 16 + l16] = (bf16_t)e;
            }
        }
        // PV with unnormalized bf16 weights (wl is same-wave only: no barrier
        // needed, lgkmcnt ordering covers the write->read dependency)
        const bf16x8 wa = *(const bf16x8*)(&wl[wave][l16][quad * 8]);
#pragma unroll
        for (int t = 0; t < 4; ++t) {
            const bf16x8 vf = *(const bf16x8*)(&vT[t * 16 + l16][quad * 8]);
            acc[t] = __builtin_amdgcn_mfma_f32_16x16x32_bf16(wa, vf, acc[t], 0, 0, 0);
        }
        __syncthreads();   // protect Kh/Kl/vT before next iteration's staging
    }

    // softmax denominators (identical accumulation order to previous version)
#pragma unroll
    for (int r = 0; r < 4; ++r) {
        float v = lsum[r];
        v += __shfl_xor(v, 1);
        v += __shfl_xor(v, 2);
        v += __shfl_xor(v, 4);
        v += __shfl_xor(v, 8);
        lsum[r] = v;
    }
    float norm[4];
#pragma unroll
    for (int r = 0; r < 4; ++r) norm[r] = 2048.f / lsum[r];

    if (l16 == 0) {
#pragma unroll
        for (int r = 0; r < 4; ++r)
            normbuf[(size_t)(b * H_ + h) * S_ + q0 + quad * 4 + r] = norm[r];
    }

#pragma unroll
    for (int t = 0; t < 4; ++t) {
#pragma unroll
        for (int r = 0; r < 4; ++r) {
            const int q = q0 + quad * 4 + r;
            ctx[((size_t)(b * S_ + q)) * D_ + h * DK_ + t * 16 + l16] =
                (bf16_t)(acc[t][r] * norm[r]);
        }
    }
}

// ---------------------------------------------------------------------------
// wout[b,h,q,:] *= normbuf[b,h,q].  Pure streaming, float4, nontemporal.
// ---------------------------------------------------------------------------
__global__ __launch_bounds__(256) void rescale_wout(
    float* __restrict__ wout,
    const float* __restrict__ normbuf)
{
    const size_t total = (size_t)B_ * H_ * S_ * (S_ / 4);  // 33.5M float4
    f32x4* wp = (f32x4*)wout;
    for (size_t i = (size_t)blockIdx.x * blockDim.x + threadIdx.x;
         i < total;
         i += (size_t)gridDim.x * blockDim.x) {
        const float n = normbuf[i >> 9];   // S_/4 = 512 float4 per row
        f32x4 w = __builtin_nontemporal_load(wp + i);
        w *= n;
        __builtin_nontemporal_store(w, wp + i);
    }
}

// ---------------------------------------------------------------------------
extern "C" void kernel_launch(void* const* d_in, const int* in_sizes, int n_in,
                              void* d_out, int out_size, void* d_ws, size_t ws_size,
                              hipStream_t stream) {
    const float* Q    = (const float*)d_in[0];
    const float* K    = (const float*)d_in[1];
    const float* V    = (const float*)d_in[2];
    const int*   mask = (const int*)d_in[3];
    const float* Wq   = (const float*)d_in[4];
    const float* bq   = (const float*)d_in[5];
    const float* Wk   = (const float*)d_in[6];
    const float* bk   = (const float*)d_in[7];
    const float* Wv   = (const float*)d_in[8];
    const float* bv   = (const float*)d_in[9];
    const float* Wo   = (const float*)d_in[10];
    const float* bo   = (const float*)d_in[11];

    const size_t BSD = (size_t)B_ * S_ * D_;  // 4,194,304
    float* out  = (float*)d_out;              // [B,S,D] fp32
    float* wout = out + BSD;                  // [B,H,S,S] fp32

    float*  qp  = (float*)d_ws;               // fp32 q (for hi/lo split)
    float*  kpf = qp + BSD;                   // fp32 k
    bf16_t* vp  = (bf16_t*)(kpf + BSD);       // bf16 v
    bf16_t* cx  = vp + BSD;                   // bf16 ctx
    unsigned long long* pk = (unsigned long long*)(cx + BSD);   // 1 MB packed mask
    float* normbuf = (float*)((unsigned*)pk + (size_t)B_ * S_ * (S_ / 32)); // 256 KB

    const int M = B_ * S_;   // 4096
    const int N = D_;        // 1024
    const int Kd = D_;       // 1024
    const dim3 ggrid((M / 64) * (N / 64));    // 1024
    const dim3 gblk(256);

    pack_mask<<<dim3(512), gblk, 0, stream>>>(mask, pk);

    gemm_bt<float, float, true><<<ggrid, gblk, 0, stream>>>(Q, Wq, bq, qp, M, N, Kd);
    gemm_bt<float, float, true><<<ggrid, gblk, 0, stream>>>(K, Wk, bk, kpf, M, N, Kd);
    gemm_bt<float, bf16_t, false><<<ggrid, gblk, 0, stream>>>(V, Wv, bv, vp, M, N, Kd);

    attn_kernel<<<dim3(B_ * H_ * (S_ / 64)), gblk, 0, stream>>>(
        qp, kpf, vp, (const unsigned*)pk, wout, normbuf, cx);

    gemm_bt<bf16_t, float, false><<<ggrid, gblk, 0, stream>>>(cx, Wo, bo, out, M, N, Kd);

    rescale_wout<<<dim3(2048), gblk, 0, stream>>>(wout, normbuf);
}

// Round 2
// 1064.592 us; speedup vs baseline: 1.0064x; 1.0064x over previous
//
#include <hip/hip_runtime.h>
#include <hip/hip_bf16.h>
#include <type_traits>

typedef __bf16 bf16_t;
typedef __attribute__((ext_vector_type(8))) __bf16 bf16x8;
typedef __attribute__((ext_vector_type(4))) float f32x4;

#define B_ 2
#define S_ 2048
#define D_ 1024
#define H_ 16
#define DK_ 64

enum { OM_F32 = 0, OM_BF16 = 1, OM_SPLIT = 2, OM_HEADT = 3 };

// split a run of 8 fp32 into bf16 hi + bf16 lo (residual) parts
__device__ inline void split8(const float* __restrict__ p, bf16x8& h, bf16x8& l) {
    float4 x0 = *(const float4*)p;
    float4 x1 = *(const float4*)(p + 4);
    float xs[8] = {x0.x, x0.y, x0.z, x0.w, x1.x, x1.y, x1.z, x1.w};
#pragma unroll
    for (int i = 0; i < 8; ++i) {
        bf16_t hh = (bf16_t)xs[i];
        h[i] = hh;
        l[i] = (bf16_t)(xs[i] - (float)hh);
    }
}
__device__ inline void hi8(const float* __restrict__ p, bf16x8& h) {
    float4 x0 = *(const float4*)p;
    float4 x1 = *(const float4*)(p + 4);
    float xs[8] = {x0.x, x0.y, x0.z, x0.w, x1.x, x1.y, x1.z, x1.w};
#pragma unroll
    for (int i = 0; i < 8; ++i) h[i] = (bf16_t)xs[i];
}

// ---------------------------------------------------------------------------
// GEMM: Y[M,N] = A[M,K] @ W[N,K]^T + bias[N].
// OMODE: F32 / BF16 (row-major [M,N]) / SPLIT (hi+lo bf16, row-major)
//        / HEADT (bf16, per-head transposed [B,H,DK,S] for the V path).
// ---------------------------------------------------------------------------
template <typename AT, int OMODE, bool SPLIT>
__global__ __launch_bounds__(256) void gemm_bt(
    const AT* __restrict__ A,
    const float* __restrict__ W,
    const float* __restrict__ bias,
    void* __restrict__ Yp,
    void* __restrict__ Y2p,
    int M, int N, int K)
{
    const int NB = N >> 6;
    const int bm = blockIdx.x / NB;
    const int bn = blockIdx.x % NB;
    const int tid  = threadIdx.x;
    const int wave = tid >> 6;
    const int lane = tid & 63;
    const int l16  = lane & 15;
    const int quad = lane >> 4;
    const int wm = wave >> 1, wn = wave & 1;

    __shared__ bf16_t Ah[64][40];
    __shared__ bf16_t Wh[64][40];
    __shared__ bf16_t Al[SPLIT ? 64 : 1][40];
    __shared__ bf16_t Wl[SPLIT ? 64 : 1][40];

    const int srow = tid >> 2;        // 0..63
    const int scol = (tid & 3) * 8;   // 0,8,16,24

    f32x4 acc[2][2];
#pragma unroll
    for (int i = 0; i < 2; ++i)
#pragma unroll
        for (int j = 0; j < 2; ++j) acc[i][j] = (f32x4){0.f, 0.f, 0.f, 0.f};

    const AT*    Arow = A + (size_t)(bm * 64 + srow) * K + scol;
    const float* Wrow = W + (size_t)(bn * 64 + srow) * K + scol;

    for (int k0 = 0; k0 < K; k0 += 32) {
        if constexpr (std::is_same_v<AT, float>) {
            bf16x8 ah, al;
            if constexpr (SPLIT) {
                split8(Arow + k0, ah, al);
                *(bf16x8*)(&Al[srow][scol]) = al;
            } else {
                hi8(Arow + k0, ah);
            }
            *(bf16x8*)(&Ah[srow][scol]) = ah;
        } else {
            *(bf16x8*)(&Ah[srow][scol]) = *(const bf16x8*)(Arow + k0);
        }
        {
            bf16x8 wh, wl;
            if constexpr (SPLIT) {
                split8(Wrow + k0, wh, wl);
                *(bf16x8*)(&Wl[srow][scol]) = wl;
            } else {
                hi8(Wrow + k0, wh);
            }
            *(bf16x8*)(&Wh[srow][scol]) = wh;
        }
        __syncthreads();

        bf16x8 afh[2], bfh[2], afl[2], bfl[2];
#pragma unroll
        for (int mi = 0; mi < 2; ++mi) {
            afh[mi] = *(const bf16x8*)(&Ah[wm * 32 + mi * 16 + l16][quad * 8]);
            if constexpr (SPLIT)
                afl[mi] = *(const bf16x8*)(&Al[wm * 32 + mi * 16 + l16][quad * 8]);
        }
#pragma unroll
        for (int ni = 0; ni < 2; ++ni) {
            bfh[ni] = *(const bf16x8*)(&Wh[wn * 32 + ni * 16 + l16][quad * 8]);
            if constexpr (SPLIT)
                bfl[ni] = *(const bf16x8*)(&Wl[wn * 32 + ni * 16 + l16][quad * 8]);
        }

#pragma unroll
        for (int mi = 0; mi < 2; ++mi)
#pragma unroll
            for (int ni = 0; ni < 2; ++ni) {
                acc[mi][ni] = __builtin_amdgcn_mfma_f32_16x16x32_bf16(
                    afh[mi], bfh[ni], acc[mi][ni], 0, 0, 0);
                if constexpr (SPLIT) {
                    acc[mi][ni] = __builtin_amdgcn_mfma_f32_16x16x32_bf16(
                        afl[mi], bfh[ni], acc[mi][ni], 0, 0, 0);
                    acc[mi][ni] = __builtin_amdgcn_mfma_f32_16x16x32_bf16(
                        afh[mi], bfl[ni], acc[mi][ni], 0, 0, 0);
                }
            }
        __syncthreads();
    }

#pragma unroll
    for (int ni = 0; ni < 2; ++ni) {
        const int col = bn * 64 + wn * 32 + ni * 16 + l16;
        const float bv = bias[col];
#pragma unroll
        for (int mi = 0; mi < 2; ++mi) {
#pragma unroll
            for (int r = 0; r < 4; ++r) {
                const int row = bm * 64 + wm * 32 + mi * 16 + quad * 4 + r;
                const float v = acc[mi][ni][r] + bv;
                if constexpr (OMODE == OM_F32) {
                    ((float*)Yp)[(size_t)row * N + col] = v;
                } else if constexpr (OMODE == OM_BF16) {
                    ((bf16_t*)Yp)[(size_t)row * N + col] = (bf16_t)v;
                } else if constexpr (OMODE == OM_SPLIT) {
                    const bf16_t hh = (bf16_t)v;
                    ((bf16_t*)Yp)[(size_t)row * N + col] = hh;
                    ((bf16_t*)Y2p)[(size_t)row * N + col] = (bf16_t)(v - (float)hh);
                } else {  // OM_HEADT: vt[b, h, dk, s]
                    const int bb  = row >> 11;          // row / S_
                    const int ss  = row & (S_ - 1);
                    const int hh2 = col >> 6;           // col / DK_
                    const int dk  = col & (DK_ - 1);
                    ((bf16_t*)Yp)[((size_t)((bb * H_ + hh2) * DK_ + dk) << 11) + ss] =
                        (bf16_t)v;
                }
            }
        }
    }
}

// ---------------------------------------------------------------------------
// Pack the int32 mask [B,S,S] into bits (1 = masked). One u64 per 64 j's.
// ---------------------------------------------------------------------------
__global__ __launch_bounds__(256) void pack_mask(
    const int* __restrict__ mask,
    unsigned long long* __restrict__ pk)
{
    const size_t nwords = (size_t)B_ * S_ * S_ / 64;  // 131072
    const int lane = threadIdx.x & 63;
    size_t w = (size_t)blockIdx.x * 4 + (threadIdx.x >> 6);
    const size_t stride = (size_t)gridDim.x * 4;
    for (; w < nwords; w += stride) {
        const int m = mask[w * 64 + lane];
        const unsigned long long bb = __ballot(m != 0);
        if (lane == 0) pk[w] = bb;
    }
}

// ---------------------------------------------------------------------------
// Single-pass attention, deferred normalization. Inputs are PRE-SPLIT by the
// GEMM epilogues: qh/ql, kh/kl bf16 [B,S,D]; vt bf16 [B,H,DK,S] (per-head
// transposed). All staging is now pure vector copies: no split VALU, no
// scalar-scatter LDS transpose (the old vT scatter was ~16-way bank-conflicted).
// ---------------------------------------------------------------------------
__global__ __launch_bounds__(256) void attn_kernel(
    const bf16_t* __restrict__ qh_g,   // [B,S,D] bf16 hi
    const bf16_t* __restrict__ ql_g,   // [B,S,D] bf16 lo
    const bf16_t* __restrict__ kh_g,   // [B,S,D] bf16 hi
    const bf16_t* __restrict__ kl_g,   // [B,S,D] bf16 lo
    const bf16_t* __restrict__ vt_g,   // [B,H,DK,S] bf16
    const unsigned* __restrict__ pm,   // packed mask bits [B,S,S/32]
    float* __restrict__ wout,          // [B,H,S,S] fp32 (unnormalized e)
    float* __restrict__ normbuf,       // [B,H,S] fp32 (2048/lsum)
    bf16_t* __restrict__ ctx)          // [B,S,D] bf16
{
    const int bid = blockIdx.x;       // B*H*(S/64) = 1024
    const int qt = bid & 31;
    const int h  = (bid >> 5) & 15;
    const int b  = bid >> 9;
    const int tid  = threadIdx.x;
    const int wave = tid >> 6;
    const int lane = tid & 63;
    const int l16  = lane & 15;
    const int quad = lane >> 4;

    const int q0 = qt * 64 + wave * 16;

    __shared__ bf16_t Kh[32][72];        // [j][dk], +8 pad
    __shared__ bf16_t Kl[32][72];
    __shared__ bf16_t vT[64][40];        // [dk][j]
    __shared__ bf16_t wl[4][16][40];     // per-wave w tile [q][j]

    // q fragments (A operand), hi/lo — direct bf16 loads, no split needed
    const size_t qoff = ((size_t)(b * S_ + q0 + l16)) * D_ + h * DK_ + quad * 8;
    const bf16x8 qh0 = *(const bf16x8*)(qh_g + qoff);
    const bf16x8 qh1 = *(const bf16x8*)(qh_g + qoff + 32);
    const bf16x8 ql0 = *(const bf16x8*)(ql_g + qoff);
    const bf16x8 ql1 = *(const bf16x8*)(ql_g + qoff + 32);

    const float scale = 0.125f;  // 1/sqrt(64)

    // cooperative staging indices
    const int srow  = tid >> 3;        // 0..31 (j) for K tiles
    const int scol  = (tid & 7) * 8;   // 0..56 (dk)
    const int srow2 = tid >> 2;        // 0..63 (dk) for V tile
    const int scol2 = (tid & 3) * 8;   // 0..24 (j)
    const bf16_t* khst = kh_g + (size_t)b * S_ * D_ + h * DK_;
    const bf16_t* klst = kl_g + (size_t)b * S_ * D_ + h * DK_;
    const bf16_t* vtst = vt_g + ((size_t)(b * H_ + h) * DK_ + srow2) * S_ + scol2;

    const unsigned* pmrow = pm + (size_t)b * S_ * (S_ / 32);
    const size_t wbase = ((size_t)(b * H_ + h)) * S_ * S_;

    float lsum[4] = {0.f, 0.f, 0.f, 0.f};
    f32x4 acc[4];
#pragma unroll
    for (int t = 0; t < 4; ++t) acc[t] = (f32x4){0.f, 0.f, 0.f, 0.f};

    for (int j0 = 0; j0 < S_; j0 += 32) {
        // ---- cooperative stage: pure vector copies ----
        {
            const size_t ko = (size_t)(j0 + srow) * D_ + scol;
            *(bf16x8*)(&Kh[srow][scol]) = *(const bf16x8*)(khst + ko);
            *(bf16x8*)(&Kl[srow][scol]) = *(const bf16x8*)(klst + ko);
            *(bf16x8*)(&vT[srow2][scol2]) = *(const bf16x8*)(vtst + j0);
        }
        // mask words: one u32 covers j0..j0+31 for row q
        unsigned mw[4];
#pragma unroll
        for (int r = 0; r < 4; ++r) {
            const int q = q0 + quad * 4 + r;
            mw[r] = pmrow[(size_t)q * (S_ / 32) + (j0 >> 5)];
        }
        __syncthreads();

#pragma unroll
        for (int sub = 0; sub < 2; ++sub) {
            const int rr = sub * 16 + l16;
            const bf16x8 kh0 = *(const bf16x8*)(&Kh[rr][quad * 8]);
            const bf16x8 kh1 = *(const bf16x8*)(&Kh[rr][32 + quad * 8]);
            const bf16x8 kl0 = *(const bf16x8*)(&Kl[rr][quad * 8]);
            const bf16x8 kl1 = *(const bf16x8*)(&Kl[rr][32 + quad * 8]);
            f32x4 c = (f32x4){0.f, 0.f, 0.f, 0.f};
            c = __builtin_amdgcn_mfma_f32_16x16x32_bf16(qh0, kh0, c, 0, 0, 0);
            c = __builtin_amdgcn_mfma_f32_16x16x32_bf16(qh1, kh1, c, 0, 0, 0);
            c = __builtin_amdgcn_mfma_f32_16x16x32_bf16(ql0, kh0, c, 0, 0, 0);
            c = __builtin_amdgcn_mfma_f32_16x16x32_bf16(ql1, kh1, c, 0, 0, 0);
            c = __builtin_amdgcn_mfma_f32_16x16x32_bf16(qh0, kl0, c, 0, 0, 0);
            c = __builtin_amdgcn_mfma_f32_16x16x32_bf16(qh1, kl1, c, 0, 0, 0);
            const int jt = j0 + sub * 16;
#pragma unroll
            for (int r = 0; r < 4; ++r) {
                const int q = q0 + quad * 4 + r;
                const int msk = (mw[r] >> (sub * 16 + l16)) & 1;
                const float e = msk ? 0.f : __expf(c[r] * scale);
                lsum[r] += e;
                __builtin_nontemporal_store(e, &wout[wbase + (size_t)q * S_ + jt + l16]);
                wl[wave][quad * 4 + r][sub * 16 + l16] = (bf16_t)e;
            }
        }
        // PV with unnormalized bf16 weights (wl is same-wave only)
        const bf16x8 wa = *(const bf16x8*)(&wl[wave][l16][quad * 8]);
#pragma unroll
        for (int t = 0; t < 4; ++t) {
            const bf16x8 vf = *(const bf16x8*)(&vT[t * 16 + l16][quad * 8]);
            acc[t] = __builtin_amdgcn_mfma_f32_16x16x32_bf16(wa, vf, acc[t], 0, 0, 0);
        }
        __syncthreads();   // protect Kh/Kl/vT before next iteration's staging
    }

    // softmax denominators (identical accumulation order)
#pragma unroll
    for (int r = 0; r < 4; ++r) {
        float v = lsum[r];
        v += __shfl_xor(v, 1);
        v += __shfl_xor(v, 2);
        v += __shfl_xor(v, 4);
        v += __shfl_xor(v, 8);
        lsum[r] = v;
    }
    float norm[4];
#pragma unroll
    for (int r = 0; r < 4; ++r) norm[r] = 2048.f / lsum[r];

    if (l16 == 0) {
#pragma unroll
        for (int r = 0; r < 4; ++r)
            normbuf[(size_t)(b * H_ + h) * S_ + q0 + quad * 4 + r] = norm[r];
    }

#pragma unroll
    for (int t = 0; t < 4; ++t) {
#pragma unroll
        for (int r = 0; r < 4; ++r) {
            const int q = q0 + quad * 4 + r;
            ctx[((size_t)(b * S_ + q)) * D_ + h * DK_ + t * 16 + l16] =
                (bf16_t)(acc[t][r] * norm[r]);
        }
    }
}

// ---------------------------------------------------------------------------
// wout[b,h,q,:] *= normbuf[b,h,q].  Pure streaming, float4, nontemporal.
// ---------------------------------------------------------------------------
__global__ __launch_bounds__(256) void rescale_wout(
    float* __restrict__ wout,
    const float* __restrict__ normbuf)
{
    const size_t total = (size_t)B_ * H_ * S_ * (S_ / 4);  // 33.5M float4
    f32x4* wp = (f32x4*)wout;
    for (size_t i = (size_t)blockIdx.x * blockDim.x + threadIdx.x;
         i < total;
         i += (size_t)gridDim.x * blockDim.x) {
        const float n = normbuf[i >> 9];   // S_/4 = 512 float4 per row
        f32x4 w = __builtin_nontemporal_load(wp + i);
        w *= n;
        __builtin_nontemporal_store(w, wp + i);
    }
}

// ---------------------------------------------------------------------------
extern "C" void kernel_launch(void* const* d_in, const int* in_sizes, int n_in,
                              void* d_out, int out_size, void* d_ws, size_t ws_size,
                              hipStream_t stream) {
    const float* Q    = (const float*)d_in[0];
    const float* K    = (const float*)d_in[1];
    const float* V    = (const float*)d_in[2];
    const int*   mask = (const int*)d_in[3];
    const float* Wq   = (const float*)d_in[4];
    const float* bq   = (const float*)d_in[5];
    const float* Wk   = (const float*)d_in[6];
    const float* bk   = (const float*)d_in[7];
    const float* Wv   = (const float*)d_in[8];
    const float* bv   = (const float*)d_in[9];
    const float* Wo   = (const float*)d_in[10];
    const float* bo   = (const float*)d_in[11];

    const size_t BSD = (size_t)B_ * S_ * D_;  // 4,194,304
    float* out  = (float*)d_out;              // [B,S,D] fp32
    float* wout = out + BSD;                  // [B,H,S,S] fp32

    bf16_t* qh = (bf16_t*)d_ws;               // pre-split q hi
    bf16_t* ql = qh + BSD;                    // pre-split q lo
    bf16_t* kh = ql + BSD;                    // pre-split k hi
    bf16_t* kl = kh + BSD;                    // pre-split k lo
    bf16_t* vt = kl + BSD;                    // per-head-transposed v
    bf16_t* cx = vt + BSD;                    // bf16 ctx
    unsigned long long* pk = (unsigned long long*)(cx + BSD);   // 1 MB packed mask
    float* normbuf = (float*)((unsigned*)pk + (size_t)B_ * S_ * (S_ / 32)); // 256 KB

    const int M = B_ * S_;   // 4096
    const int N = D_;        // 1024
    const int Kd = D_;       // 1024
    const dim3 ggrid((M / 64) * (N / 64));    // 1024
    const dim3 gblk(256);

    pack_mask<<<dim3(512), gblk, 0, stream>>>(mask, pk);

    gemm_bt<float, OM_SPLIT, true><<<ggrid, gblk, 0, stream>>>(Q, Wq, bq, qh, ql, M, N, Kd);
    gemm_bt<float, OM_SPLIT, true><<<ggrid, gblk, 0, stream>>>(K, Wk, bk, kh, kl, M, N, Kd);
    gemm_bt<float, OM_HEADT, false><<<ggrid, gblk, 0, stream>>>(V, Wv, bv, vt, nullptr, M, N, Kd);

    attn_kernel<<<dim3(B_ * H_ * (S_ / 64)), gblk, 0, stream>>>(
        qh, ql, kh, kl, vt, (const unsigned*)pk, wout, normbuf, cx);

    gemm_bt<bf16_t, OM_F32, false><<<ggrid, gblk, 0, stream>>>(cx, Wo, bo, out, nullptr, M, N, Kd);

    rescale_wout<<<dim3(2048), gblk, 0, stream>>>(wout, normbuf);
}